// Round 1
// baseline (14915.990 us; speedup 1.0000x reference)
//
#include <hip/hip_runtime.h>

#define TT 2048
#define WD 768
#define HH 512
#define G4 2048      // 4*H
#define NC 5
#define KWG 32       // workgroups per direction in recurrence

// ---------------------------------------------------------------------------
// Kernel 1: zin[t][g] = emb[sent[t]] . Wih[g] + bih[g] + bhh[g]   (both dirs)
// 128x128 tile, BK=16, 256 threads, 8x8 per thread, fp32.
// ---------------------------------------------------------------------------
__global__ __launch_bounds__(256) void zin_gemm(
    const int* __restrict__ sent, const float* __restrict__ emb,
    const float* __restrict__ Wih_f, const float* __restrict__ bih_f, const float* __restrict__ bhh_f,
    const float* __restrict__ Wih_b, const float* __restrict__ bih_b, const float* __restrict__ bhh_b,
    float* __restrict__ zin_f, float* __restrict__ zin_b)
{
    const int dirn = blockIdx.z;
    const float* Wih = dirn ? Wih_b : Wih_f;
    const float* bih = dirn ? bih_b : bih_f;
    const float* bhh = dirn ? bhh_b : bhh_f;
    float* zin = dirn ? zin_b : zin_f;

    __shared__ float As[16][128];
    __shared__ float Bs[16][128];

    const int tid = threadIdx.x;
    const int t0 = blockIdx.y * 128;
    const int g0 = blockIdx.x * 128;
    const int tm = tid >> 4, tn = tid & 15;

    float acc[8][8];
#pragma unroll
    for (int a = 0; a < 8; a++)
#pragma unroll
        for (int b = 0; b < 8; b++) acc[a][b] = 0.f;

    for (int kt = 0; kt < 48; ++kt) {
        const int k0 = kt * 16;
#pragma unroll
        for (int u = 0; u < 2; ++u) {
            const int s = tid * 2 + u;
            const int m = s >> 2, kq = s & 3;
            const int rowA = sent[t0 + m];
            float4 av = *(const float4*)(emb + (size_t)rowA * WD + k0 + kq * 4);
            As[kq * 4 + 0][m] = av.x; As[kq * 4 + 1][m] = av.y;
            As[kq * 4 + 2][m] = av.z; As[kq * 4 + 3][m] = av.w;
            float4 bv = *(const float4*)(Wih + (size_t)(g0 + m) * WD + k0 + kq * 4);
            Bs[kq * 4 + 0][m] = bv.x; Bs[kq * 4 + 1][m] = bv.y;
            Bs[kq * 4 + 2][m] = bv.z; Bs[kq * 4 + 3][m] = bv.w;
        }
        __syncthreads();
#pragma unroll
        for (int kk = 0; kk < 16; ++kk) {
            float4 a0 = *(const float4*)&As[kk][tm * 8];
            float4 a1 = *(const float4*)&As[kk][tm * 8 + 4];
            float4 b0 = *(const float4*)&Bs[kk][tn * 8];
            float4 b1 = *(const float4*)&Bs[kk][tn * 8 + 4];
            float av8[8] = {a0.x, a0.y, a0.z, a0.w, a1.x, a1.y, a1.z, a1.w};
            float bv8[8] = {b0.x, b0.y, b0.z, b0.w, b1.x, b1.y, b1.z, b1.w};
#pragma unroll
            for (int a = 0; a < 8; a++)
#pragma unroll
                for (int b = 0; b < 8; b++) acc[a][b] += av8[a] * bv8[b];
        }
        __syncthreads();
    }
    float bias[8];
#pragma unroll
    for (int b = 0; b < 8; b++) { int g = g0 + tn * 8 + b; bias[b] = bih[g] + bhh[g]; }
#pragma unroll
    for (int a = 0; a < 8; a++) {
        const int t = t0 + tm * 8 + a;
        float* op = zin + (size_t)t * G4 + g0 + tn * 8;
        float4 o0 = {acc[a][0] + bias[0], acc[a][1] + bias[1], acc[a][2] + bias[2], acc[a][3] + bias[3]};
        float4 o1 = {acc[a][4] + bias[4], acc[a][5] + bias[5], acc[a][6] + bias[6], acc[a][7] + bias[7]};
        *(float4*)op = o0; *(float4*)(op + 4) = o1;
    }
}

// ---------------------------------------------------------------------------
// Kernel 2: LSTM recurrence, both directions. 64 wgs x 256 threads.
// wg (d,k): hidden slice n in [k*16, k*16+16), 64 gate rows x 512 cols of Whh
// held in registers (32 float4/thread). Per step: dot with h_prev (LDS),
// 4-lane shuffle reduce, gate math in threads 0..15, h broadcast via global
// + device-scope counter sync.
// ---------------------------------------------------------------------------
__global__ __launch_bounds__(256, 1) void lstm_rec(
    const float* __restrict__ zin_f, const float* __restrict__ zin_b,
    const float* __restrict__ Whh_f, const float* __restrict__ Whh_b,
    float* __restrict__ h_f, float* __restrict__ h_b,
    int* __restrict__ cnt)
{
    const int bid = blockIdx.x;
    const int d = bid >> 5;      // 0 fwd, 1 bwd
    const int k = bid & 31;
    const float* zin = d ? zin_b : zin_f;
    const float* Whh = d ? Whh_b : Whh_f;
    float* hout = d ? h_b : h_f;
    int* mycnt = cnt + d * TT;

    const int tid = threadIdx.x;
    const int r = tid >> 2;          // local row 0..63
    const int q = tid & 3;           // col quarter
    const int gate = r >> 4;         // 0..3 (i,f,g,o)
    const int j = r & 15;
    const int grow = gate * 512 + k * 16 + j;   // global gate row

    float4 w[32];
    const float4* wp = (const float4*)(Whh + (size_t)grow * HH + q * 128);
#pragma unroll
    for (int i = 0; i < 32; i++) w[i] = wp[i];

    __shared__ float hs[HH];
    __shared__ float zbuf[64];

    const bool isg = (tid < 16);
    float c = 0.f;
    const int n_glob = k * 16 + tid;   // valid for gate threads

    for (int it = 0; it < TT; ++it) {
        const int t = d ? (TT - 1 - it) : it;
        float z0 = 0.f, z1 = 0.f, z2 = 0.f, z3 = 0.f;
        if (isg) {  // prefetch input projection (independent of h chain)
            const float* zt = zin + (size_t)t * G4 + n_glob;
            z0 = zt[0]; z1 = zt[512]; z2 = zt[1024]; z3 = zt[1536];
        }
        float part = 0.f;
        if (it > 0) {
            if (tid == 0) {
                while (__hip_atomic_load(&mycnt[it - 1], __ATOMIC_ACQUIRE,
                                         __HIP_MEMORY_SCOPE_AGENT) < KWG) { }
            }
            __syncthreads();
            const int tprev = d ? (t + 1) : (t - 1);
            const float4* hp = (const float4*)(hout + (size_t)tprev * HH);
            if (tid < 128) ((float4*)hs)[tid] = hp[tid];
            __syncthreads();
            const float4* hv4 = ((const float4*)hs) + q * 32;
#pragma unroll
            for (int i = 0; i < 32; i++) {
                float4 hh = hv4[i];
                part += w[i].x * hh.x + w[i].y * hh.y + w[i].z * hh.z + w[i].w * hh.w;
            }
        }
        part += __shfl_xor(part, 1);
        part += __shfl_xor(part, 2);
        if (q == 0) zbuf[r] = part;
        __syncthreads();
        if (isg) {
            const float zi = z0 + zbuf[tid];
            const float zf = z1 + zbuf[16 + tid];
            const float zg = z2 + zbuf[32 + tid];
            const float zo = z3 + zbuf[48 + tid];
            const float gi = 1.f / (1.f + expf(-zi));
            const float gf = 1.f / (1.f + expf(-zf));
            const float gg = tanhf(zg);
            const float go = 1.f / (1.f + expf(-zo));
            c = gf * c + gi * gg;
            const float hval = go * tanhf(c);
            hout[(size_t)t * HH + n_glob] = hval;
        }
        __threadfence();
        __syncthreads();
        if (tid == 0) {
            __hip_atomic_fetch_add(&mycnt[it], 1, __ATOMIC_RELEASE,
                                   __HIP_MEMORY_SCOPE_AGENT);
        }
    }
}

// ---------------------------------------------------------------------------
// Kernel 3: feats[t] = [h_f[t] | h_b[t]] . fc_w[i] + fc_b[i].  One wave per t.
// ---------------------------------------------------------------------------
__global__ void feats_kernel(const float* __restrict__ h_f, const float* __restrict__ h_b,
                             const float* __restrict__ fc_w, const float* __restrict__ fc_b,
                             float* __restrict__ feats)
{
    const int t = blockIdx.x;
    const int l = threadIdx.x;
    float acc[NC] = {0.f, 0.f, 0.f, 0.f, 0.f};
    for (int m = 0; m < 16; ++m) {
        const int cg = l + m * 64;
        const float hv = (cg < HH) ? h_f[(size_t)t * HH + cg]
                                   : h_b[(size_t)t * HH + cg - HH];
#pragma unroll
        for (int i = 0; i < NC; i++) acc[i] += hv * fc_w[i * (2 * HH) + cg];
    }
#pragma unroll
    for (int i = 0; i < NC; i++) {
#pragma unroll
        for (int off = 32; off; off >>= 1) acc[i] += __shfl_xor(acc[i], off);
    }
    if (l == 0) {
#pragma unroll
        for (int i = 0; i < NC; i++) feats[(size_t)t * NC + i] = acc[i] + fc_b[i];
    }
}

// ---------------------------------------------------------------------------
// Kernel 4: Viterbi forward + backtrack. 1 block, 64 threads (single wave).
// All lanes redundantly run the 5x5 max-plus recurrence in registers.
// ---------------------------------------------------------------------------
__global__ void viterbi_kernel(const float* __restrict__ feats,
                               const float* __restrict__ trans,
                               float* __restrict__ out)
{
    __shared__ float fs[TT * NC];     // 40 KB
    __shared__ int par[TT];           // packed 3-bit parents, 8 KB
    __shared__ float pathv[TT];       // 8 KB
    const int tid = threadIdx.x;
    for (int i = tid; i < TT * NC; i += 64) fs[i] = feats[i];
    float tr[25];
#pragma unroll
    for (int i = 0; i < 25; i++) tr[i] = trans[i];
    __syncthreads();

    float layer[NC];
#pragma unroll
    for (int i = 0; i < NC; i++) layer[i] = fs[i] + tr[i * 5 + 3];  // + trans[:,START=3]

    for (int s = 0; s < TT - 1; ++s) {
        const float* ft = &fs[(s + 1) * NC];
        float nl[NC]; int pk = 0;
#pragma unroll
        for (int i = 0; i < NC; i++) {
            float best = tr[i * 5 + 0] + layer[0]; int bj = 0;
#pragma unroll
            for (int jj = 1; jj < NC; jj++) {
                const float v = tr[i * 5 + jj] + layer[jj];
                if (v > best) { best = v; bj = jj; }   // strict >: first-max, matches argmax
            }
            nl[i] = ft[i] + best;
            pk |= bj << (3 * i);
        }
#pragma unroll
        for (int i = 0; i < NC; i++) layer[i] = nl[i];
        if (tid == 0) par[s] = pk;
    }
    // final = layer + trans[END=4]
    float best = layer[0] + tr[20]; int idx0 = 0;
#pragma unroll
    for (int jj = 1; jj < NC; jj++) {
        const float v = layer[jj] + tr[20 + jj];
        if (v > best) { best = v; idx0 = jj; }
    }
    __syncthreads();
    if (tid == 0) {
        pathv[TT - 1] = (float)idx0;
        int idx = idx0;
        for (int s = TT - 2; s >= 0; --s) {
            idx = (par[s] >> (3 * idx)) & 7;
            pathv[s] = (float)idx;
        }
        out[TT] = best;   // path_score
    }
    __syncthreads();
    for (int i = tid; i < TT; i += 64) out[i] = pathv[i];
}

// ---------------------------------------------------------------------------
extern "C" void kernel_launch(void* const* d_in, const int* in_sizes, int n_in,
                              void* d_out, int out_size, void* d_ws, size_t ws_size,
                              hipStream_t stream) {
    const int*   sent   = (const int*)d_in[0];
    const float* emb    = (const float*)d_in[1];
    const float* Wih_f  = (const float*)d_in[2];
    const float* Whh_f  = (const float*)d_in[3];
    const float* bih_f  = (const float*)d_in[4];
    const float* bhh_f  = (const float*)d_in[5];
    const float* Wih_b  = (const float*)d_in[6];
    const float* Whh_b  = (const float*)d_in[7];
    const float* bih_b  = (const float*)d_in[8];
    const float* bhh_b  = (const float*)d_in[9];
    const float* fc_w   = (const float*)d_in[10];
    const float* fc_b   = (const float*)d_in[11];
    const float* trans  = (const float*)d_in[12];
    float* out = (float*)d_out;

    char* ws = (char*)d_ws;
    int*   cnt   = (int*)ws;                                  // 2*2048 ints
    float* zin_f = (float*)(ws + 65536);                      // 16 MB
    float* zin_b = (float*)(ws + 65536 + (size_t)16777216);   // 16 MB
    float* h_f   = (float*)(ws + 65536 + (size_t)33554432);   // 4 MB
    float* h_b   = (float*)(ws + 65536 + (size_t)37748736);   // 4 MB
    float* feats = (float*)(ws + 65536 + (size_t)41943040);   // 40 KB

    hipMemsetAsync(cnt, 0, 2 * TT * sizeof(int), stream);

    dim3 gg(G4 / 128, TT / 128, 2);
    zin_gemm<<<gg, 256, 0, stream>>>(sent, emb, Wih_f, bih_f, bhh_f,
                                     Wih_b, bih_b, bhh_b, zin_f, zin_b);

    lstm_rec<<<2 * KWG, 256, 0, stream>>>(zin_f, zin_b, Whh_f, Whh_b, h_f, h_b, cnt);

    feats_kernel<<<TT, 64, 0, stream>>>(h_f, h_b, fc_w, fc_b, feats);

    viterbi_kernel<<<1, 64, 0, stream>>>(feats, trans, out);
}

// Round 2
// 11939.626 us; speedup vs baseline: 1.2493x; 1.2493x over previous
//
#include <hip/hip_runtime.h>

#define TT 2048
#define WD 768
#define HH 512
#define G4 2048      // 4*H
#define NC 5
#define NWG 32       // fused workgroups; each owns 16 hidden units per direction

// ---------------------------------------------------------------------------
// Kernel 1: zin[t][g] = emb[sent[t]] . Wih[g] + bih[g] + bhh[g]   (both dirs)
// ---------------------------------------------------------------------------
__global__ __launch_bounds__(256) void zin_gemm(
    const int* __restrict__ sent, const float* __restrict__ emb,
    const float* __restrict__ Wih_f, const float* __restrict__ bih_f, const float* __restrict__ bhh_f,
    const float* __restrict__ Wih_b, const float* __restrict__ bih_b, const float* __restrict__ bhh_b,
    float* __restrict__ zin_f, float* __restrict__ zin_b)
{
    const int dirn = blockIdx.z;
    const float* Wih = dirn ? Wih_b : Wih_f;
    const float* bih = dirn ? bih_b : bih_f;
    const float* bhh = dirn ? bhh_b : bhh_f;
    float* zin = dirn ? zin_b : zin_f;

    __shared__ float As[16][128];
    __shared__ float Bs[16][128];

    const int tid = threadIdx.x;
    const int t0 = blockIdx.y * 128;
    const int g0 = blockIdx.x * 128;
    const int tm = tid >> 4, tn = tid & 15;

    float acc[8][8];
#pragma unroll
    for (int a = 0; a < 8; a++)
#pragma unroll
        for (int b = 0; b < 8; b++) acc[a][b] = 0.f;

    for (int kt = 0; kt < 48; ++kt) {
        const int k0 = kt * 16;
#pragma unroll
        for (int u = 0; u < 2; ++u) {
            const int s = tid * 2 + u;
            const int m = s >> 2, kq = s & 3;
            const int rowA = sent[t0 + m];
            float4 av = *(const float4*)(emb + (size_t)rowA * WD + k0 + kq * 4);
            As[kq * 4 + 0][m] = av.x; As[kq * 4 + 1][m] = av.y;
            As[kq * 4 + 2][m] = av.z; As[kq * 4 + 3][m] = av.w;
            float4 bv = *(const float4*)(Wih + (size_t)(g0 + m) * WD + k0 + kq * 4);
            Bs[kq * 4 + 0][m] = bv.x; Bs[kq * 4 + 1][m] = bv.y;
            Bs[kq * 4 + 2][m] = bv.z; Bs[kq * 4 + 3][m] = bv.w;
        }
        __syncthreads();
#pragma unroll
        for (int kk = 0; kk < 16; ++kk) {
            float4 a0 = *(const float4*)&As[kk][tm * 8];
            float4 a1 = *(const float4*)&As[kk][tm * 8 + 4];
            float4 b0 = *(const float4*)&Bs[kk][tn * 8];
            float4 b1 = *(const float4*)&Bs[kk][tn * 8 + 4];
            float av8[8] = {a0.x, a0.y, a0.z, a0.w, a1.x, a1.y, a1.z, a1.w};
            float bv8[8] = {b0.x, b0.y, b0.z, b0.w, b1.x, b1.y, b1.z, b1.w};
#pragma unroll
            for (int a = 0; a < 8; a++)
#pragma unroll
                for (int b = 0; b < 8; b++) acc[a][b] += av8[a] * bv8[b];
        }
        __syncthreads();
    }
    float bias[8];
#pragma unroll
    for (int b = 0; b < 8; b++) { int g = g0 + tn * 8 + b; bias[b] = bih[g] + bhh[g]; }
#pragma unroll
    for (int a = 0; a < 8; a++) {
        const int t = t0 + tm * 8 + a;
        float* op = zin + (size_t)t * G4 + g0 + tn * 8;
        float4 o0 = {acc[a][0] + bias[0], acc[a][1] + bias[1], acc[a][2] + bias[2], acc[a][3] + bias[3]};
        float4 o1 = {acc[a][4] + bias[4], acc[a][5] + bias[5], acc[a][6] + bias[6], acc[a][7] + bias[7]};
        *(float4*)op = o0; *(float4*)(op + 4) = o1;
    }
}

// ---------------------------------------------------------------------------
// Kernel 2: fused BiLSTM recurrence. 32 wgs x 256 threads (4 waves).
// wg k owns hidden units [k*16, k*16+16) of BOTH directions.
// Thread map: wave q = tid>>6 = column segment (128 cols), lane r = tid&63 =
// gate row (gate=r>>4, j=r&15). Weights (2 dirs x 32 float4 = 256 VGPRs)
// pinned in registers via asm volatile loads.
// h exchange: sc1 (agent-scope relaxed atomic) stores/loads — write-through
// to Infinity Cache, no wbl2/threadfence per step. Per-wg flags, parallel
// lane polling with ACQUIRE.
// ---------------------------------------------------------------------------
#define PINLD(dst, ptr, OFF) \
    asm volatile("global_load_dwordx4 %0, %1, off offset:" #OFF : "=v"(dst) : "v"(ptr))
#define PL8(w, p, I, O0,O1,O2,O3,O4,O5,O6,O7) \
    PINLD(w[I+0],p,O0); PINLD(w[I+1],p,O1); PINLD(w[I+2],p,O2); PINLD(w[I+3],p,O3); \
    PINLD(w[I+4],p,O4); PINLD(w[I+5],p,O5); PINLD(w[I+6],p,O6); PINLD(w[I+7],p,O7)

__global__ __launch_bounds__(256, 1) void lstm_rec(
    const float* __restrict__ zin_f, const float* __restrict__ zin_b,
    const float* __restrict__ Whh_f, const float* __restrict__ Whh_b,
    float* __restrict__ h_f, float* __restrict__ h_b,
    int* __restrict__ flg_f, int* __restrict__ flg_b)
{
    const int k = blockIdx.x;
    const int tid = threadIdx.x;
    const int q = tid >> 6;          // wave index = column segment
    const int r = tid & 63;          // gate row within wg
    const int gate = r >> 4, j = r & 15;
    const int grow = gate * HH + k * 16 + j;       // global gate row [0,2048)

    const float4* pf = (const float4*)(Whh_f + (size_t)grow * HH + q * 128);
    const float4* pb = (const float4*)(Whh_b + (size_t)grow * HH + q * 128);

    float4 wf[32], wb[32];
    PL8(wf, pf, 0,    0,16,32,48,64,80,96,112);
    PL8(wf, pf, 8,    128,144,160,176,192,208,224,240);
    PL8(wf, pf, 16,   256,272,288,304,320,336,352,368);
    PL8(wf, pf, 24,   384,400,416,432,448,464,480,496);
    PL8(wb, pb, 0,    0,16,32,48,64,80,96,112);
    PL8(wb, pb, 8,    128,144,160,176,192,208,224,240);
    PL8(wb, pb, 16,   256,272,288,304,320,336,352,368);
    PL8(wb, pb, 24,   384,400,416,432,448,464,480,496);
    asm volatile("s_waitcnt vmcnt(0)" ::: "memory");

    __shared__ float hsf[HH], hsb[HH];
    __shared__ float zf[256], zb[256];

    float cf = 0.f, cb = 0.f;
    const int n = k * 16 + tid;      // hidden index (valid for tid<16)
    const int i2 = tid * 2;

    for (int it = 0; it < TT; ++it) {
        const int tf = it, tb = TT - 1 - it;

        // zin prefetch (plain cached loads, constant data)
        float zfi0=0, zfi1=0, zfi2=0, zfi3=0, zbi0=0, zbi1=0, zbi2=0, zbi3=0;
        if (tid < 16) {
            const float* ztf = zin_f + (size_t)tf * G4 + n;
            zfi0 = ztf[0]; zfi1 = ztf[512]; zfi2 = ztf[1024]; zfi3 = ztf[1536];
            const float* ztb = zin_b + (size_t)tb * G4 + n;
            zbi0 = ztb[0]; zbi1 = ztb[512]; zbi2 = ztb[1024]; zbi3 = ztb[1536];
        }

        // ---- fwd spin: wave0, one flag per lane, parallel ----
        if (tid < 64 && it > 0) {
            int v;
            do {
                v = 1;
                if (tid < 32)
                    v = __hip_atomic_load(&flg_f[tid * TT + it - 1],
                                          __ATOMIC_ACQUIRE, __HIP_MEMORY_SCOPE_AGENT);
            } while (__ballot(v != 1));
        }
        __syncthreads();                                           // B0

        if (it > 0) {
            const float* hp = h_f + (size_t)(tf - 1) * HH;
            float a = __hip_atomic_load(&hp[i2],     __ATOMIC_RELAXED, __HIP_MEMORY_SCOPE_AGENT);
            float b = __hip_atomic_load(&hp[i2 + 1], __ATOMIC_RELAXED, __HIP_MEMORY_SCOPE_AGENT);
            hsf[i2] = a; hsf[i2 + 1] = b;
        }
        __syncthreads();                                           // B1

        float part = 0.f;
        if (it > 0) {
            const float4* hv = ((const float4*)hsf) + (q << 5);    // wave-uniform: broadcast reads
#pragma unroll
            for (int i = 0; i < 32; ++i) {
                float4 h4 = hv[i];
                part += wf[i].x * h4.x + wf[i].y * h4.y + wf[i].z * h4.z + wf[i].w * h4.w;
            }
        }
        zf[(q << 6) + r] = part;
        __syncthreads();                                           // B2

        // wave1 spins for bwd while wave0 does fwd gate math
        if (tid >= 64 && tid < 128 && it > 0) {
            const int l = tid - 64;
            int v;
            do {
                v = 1;
                if (l < 32)
                    v = __hip_atomic_load(&flg_b[l * TT + it - 1],
                                          __ATOMIC_ACQUIRE, __HIP_MEMORY_SCOPE_AGENT);
            } while (__ballot(v != 1));
        }
        if (tid < 16) {
            float s0 = 0, s1 = 0, s2 = 0, s3 = 0;
#pragma unroll
            for (int qq = 0; qq < 4; ++qq) {
                const int base = qq * 64 + tid;
                s0 += zf[base]; s1 += zf[base + 16]; s2 += zf[base + 32]; s3 += zf[base + 48];
            }
            const float gi = 1.f / (1.f + expf(-(zfi0 + s0)));
            const float gf = 1.f / (1.f + expf(-(zfi1 + s1)));
            const float gg = tanhf(zfi2 + s2);
            const float go = 1.f / (1.f + expf(-(zfi3 + s3)));
            cf = gf * cf + gi * gg;
            const float hval = go * tanhf(cf);
            __hip_atomic_store(&h_f[(size_t)tf * HH + n], hval,
                               __ATOMIC_RELAXED, __HIP_MEMORY_SCOPE_AGENT);
        }
        __syncthreads();                                           // B3 (drains h_f stores)
        if (tid == 0)
            __hip_atomic_store(&flg_f[k * TT + it], 1,
                               __ATOMIC_RELEASE, __HIP_MEMORY_SCOPE_AGENT);

        if (it > 0) {
            const float* hp = h_b + (size_t)(tb + 1) * HH;
            float a = __hip_atomic_load(&hp[i2],     __ATOMIC_RELAXED, __HIP_MEMORY_SCOPE_AGENT);
            float b = __hip_atomic_load(&hp[i2 + 1], __ATOMIC_RELAXED, __HIP_MEMORY_SCOPE_AGENT);
            hsb[i2] = a; hsb[i2 + 1] = b;
        }
        __syncthreads();                                           // B4

        part = 0.f;
        if (it > 0) {
            const float4* hv = ((const float4*)hsb) + (q << 5);
#pragma unroll
            for (int i = 0; i < 32; ++i) {
                float4 h4 = hv[i];
                part += wb[i].x * h4.x + wb[i].y * h4.y + wb[i].z * h4.z + wb[i].w * h4.w;
            }
        }
        zb[(q << 6) + r] = part;
        __syncthreads();                                           // B5

        if (tid < 16) {
            float s0 = 0, s1 = 0, s2 = 0, s3 = 0;
#pragma unroll
            for (int qq = 0; qq < 4; ++qq) {
                const int base = qq * 64 + tid;
                s0 += zb[base]; s1 += zb[base + 16]; s2 += zb[base + 32]; s3 += zb[base + 48];
            }
            const float gi = 1.f / (1.f + expf(-(zbi0 + s0)));
            const float gf = 1.f / (1.f + expf(-(zbi1 + s1)));
            const float gg = tanhf(zbi2 + s2);
            const float go = 1.f / (1.f + expf(-(zbi3 + s3)));
            cb = gf * cb + gi * gg;
            const float hval = go * tanhf(cb);
            __hip_atomic_store(&h_b[(size_t)tb * HH + n], hval,
                               __ATOMIC_RELAXED, __HIP_MEMORY_SCOPE_AGENT);
        }
        __syncthreads();                                           // B6 (drains h_b stores)
        if (tid == 0)
            __hip_atomic_store(&flg_b[k * TT + it], 1,
                               __ATOMIC_RELEASE, __HIP_MEMORY_SCOPE_AGENT);
    }
}

// ---------------------------------------------------------------------------
// Kernel 3: feats[t] = [h_f[t] | h_b[t]] . fc_w[i] + fc_b[i].  One wave per t.
// ---------------------------------------------------------------------------
__global__ void feats_kernel(const float* __restrict__ h_f, const float* __restrict__ h_b,
                             const float* __restrict__ fc_w, const float* __restrict__ fc_b,
                             float* __restrict__ feats)
{
    const int t = blockIdx.x;
    const int l = threadIdx.x;
    float acc[NC] = {0.f, 0.f, 0.f, 0.f, 0.f};
    for (int m = 0; m < 16; ++m) {
        const int cg = l + m * 64;
        const float hv = (cg < HH) ? h_f[(size_t)t * HH + cg]
                                   : h_b[(size_t)t * HH + cg - HH];
#pragma unroll
        for (int i = 0; i < NC; i++) acc[i] += hv * fc_w[i * (2 * HH) + cg];
    }
#pragma unroll
    for (int i = 0; i < NC; i++) {
#pragma unroll
        for (int off = 32; off; off >>= 1) acc[i] += __shfl_xor(acc[i], off);
    }
    if (l == 0) {
#pragma unroll
        for (int i = 0; i < NC; i++) feats[(size_t)t * NC + i] = acc[i] + fc_b[i];
    }
}

// ---------------------------------------------------------------------------
// Kernel 4: Viterbi forward + backtrack. 1 block, 64 threads.
// ---------------------------------------------------------------------------
__global__ void viterbi_kernel(const float* __restrict__ feats,
                               const float* __restrict__ trans,
                               float* __restrict__ out)
{
    __shared__ float fs[TT * NC];
    __shared__ int par[TT];
    __shared__ float pathv[TT];
    const int tid = threadIdx.x;
    for (int i = tid; i < TT * NC; i += 64) fs[i] = feats[i];
    float tr[25];
#pragma unroll
    for (int i = 0; i < 25; i++) tr[i] = trans[i];
    __syncthreads();

    float layer[NC];
#pragma unroll
    for (int i = 0; i < NC; i++) layer[i] = fs[i] + tr[i * 5 + 3];

    for (int s = 0; s < TT - 1; ++s) {
        const float* ft = &fs[(s + 1) * NC];
        float nl[NC]; int pk = 0;
#pragma unroll
        for (int i = 0; i < NC; i++) {
            float best = tr[i * 5 + 0] + layer[0]; int bj = 0;
#pragma unroll
            for (int jj = 1; jj < NC; jj++) {
                const float v = tr[i * 5 + jj] + layer[jj];
                if (v > best) { best = v; bj = jj; }
            }
            nl[i] = ft[i] + best;
            pk |= bj << (3 * i);
        }
#pragma unroll
        for (int i = 0; i < NC; i++) layer[i] = nl[i];
        if (tid == 0) par[s] = pk;
    }
    float best = layer[0] + tr[20]; int idx0 = 0;
#pragma unroll
    for (int jj = 1; jj < NC; jj++) {
        const float v = layer[jj] + tr[20 + jj];
        if (v > best) { best = v; idx0 = jj; }
    }
    __syncthreads();
    if (tid == 0) {
        pathv[TT - 1] = (float)idx0;
        int idx = idx0;
        for (int s = TT - 2; s >= 0; --s) {
            idx = (par[s] >> (3 * idx)) & 7;
            pathv[s] = (float)idx;
        }
        out[TT] = best;
    }
    __syncthreads();
    for (int i = tid; i < TT; i += 64) out[i] = pathv[i];
}

// ---------------------------------------------------------------------------
extern "C" void kernel_launch(void* const* d_in, const int* in_sizes, int n_in,
                              void* d_out, int out_size, void* d_ws, size_t ws_size,
                              hipStream_t stream) {
    const int*   sent   = (const int*)d_in[0];
    const float* emb    = (const float*)d_in[1];
    const float* Wih_f  = (const float*)d_in[2];
    const float* Whh_f  = (const float*)d_in[3];
    const float* bih_f  = (const float*)d_in[4];
    const float* bhh_f  = (const float*)d_in[5];
    const float* Wih_b  = (const float*)d_in[6];
    const float* Whh_b  = (const float*)d_in[7];
    const float* bih_b  = (const float*)d_in[8];
    const float* bhh_b  = (const float*)d_in[9];
    const float* fc_w   = (const float*)d_in[10];
    const float* fc_b   = (const float*)d_in[11];
    const float* trans  = (const float*)d_in[12];
    float* out = (float*)d_out;

    char* ws = (char*)d_ws;
    int*   flg_f = (int*)ws;                                   // 256 KB (poison != 1, no memset needed)
    int*   flg_b = (int*)(ws + 262144);                        // 256 KB
    float* zin_f = (float*)(ws + 524288);                      // 16 MB
    float* zin_b = (float*)(ws + 524288 + (size_t)16777216);   // 16 MB
    float* h_f   = (float*)(ws + 524288 + (size_t)33554432);   // 4 MB
    float* h_b   = (float*)(ws + 524288 + (size_t)37748736);   // 4 MB
    float* feats = (float*)(ws + 524288 + (size_t)41943040);   // 40 KB

    dim3 gg(G4 / 128, TT / 128, 2);
    zin_gemm<<<gg, 256, 0, stream>>>(sent, emb, Wih_f, bih_f, bhh_f,
                                     Wih_b, bih_b, bhh_b, zin_f, zin_b);

    lstm_rec<<<NWG, 256, 0, stream>>>(zin_f, zin_b, Whh_f, Whh_b, h_f, h_b, flg_f, flg_b);

    feats_kernel<<<TT, 64, 0, stream>>>(h_f, h_b, fc_w, fc_b, feats);

    viterbi_kernel<<<1, 64, 0, stream>>>(feats, trans, out);
}

// Round 6
// 5648.746 us; speedup vs baseline: 2.6406x; 2.1137x over previous
//
#include <hip/hip_runtime.h>

#define TT 2048
#define WD 768
#define HH 512
#define G4 2048      // 4*H
#define NC 5
#define SENT 0xFFFFFFFFu   // our own sentinel (-NaN); |h|<1 can never produce it.
                           // h buffers memset to 0xFF at every launch.

typedef float f4 __attribute__((ext_vector_type(4)));

// ---------------------------------------------------------------------------
// Kernel 1: zin[t][g] = emb[sent[t]] . Wih[g] + bih[g] + bhh[g]   (both dirs)
// ---------------------------------------------------------------------------
__global__ __launch_bounds__(256) void zin_gemm(
    const int* __restrict__ sent, const float* __restrict__ emb,
    const float* __restrict__ Wih_f, const float* __restrict__ bih_f, const float* __restrict__ bhh_f,
    const float* __restrict__ Wih_b, const float* __restrict__ bih_b, const float* __restrict__ bhh_b,
    float* __restrict__ zin_f, float* __restrict__ zin_b)
{
    const int dirn = blockIdx.z;
    const float* Wih = dirn ? Wih_b : Wih_f;
    const float* bih = dirn ? bih_b : bih_f;
    const float* bhh = dirn ? bhh_b : bhh_f;
    float* zin = dirn ? zin_b : zin_f;

    __shared__ float As[16][128];
    __shared__ float Bs[16][128];

    const int tid = threadIdx.x;
    const int t0 = blockIdx.y * 128;
    const int g0 = blockIdx.x * 128;
    const int tm = tid >> 4, tn = tid & 15;

    float acc[8][8];
#pragma unroll
    for (int a = 0; a < 8; a++)
#pragma unroll
        for (int b = 0; b < 8; b++) acc[a][b] = 0.f;

    for (int kt = 0; kt < 48; ++kt) {
        const int k0 = kt * 16;
#pragma unroll
        for (int u = 0; u < 2; ++u) {
            const int s = tid * 2 + u;
            const int m = s >> 2, kq = s & 3;
            const int rowA = sent[t0 + m];
            float4 av = *(const float4*)(emb + (size_t)rowA * WD + k0 + kq * 4);
            As[kq * 4 + 0][m] = av.x; As[kq * 4 + 1][m] = av.y;
            As[kq * 4 + 2][m] = av.z; As[kq * 4 + 3][m] = av.w;
            float4 bv = *(const float4*)(Wih + (size_t)(g0 + m) * WD + k0 + kq * 4);
            Bs[kq * 4 + 0][m] = bv.x; Bs[kq * 4 + 1][m] = bv.y;
            Bs[kq * 4 + 2][m] = bv.z; Bs[kq * 4 + 3][m] = bv.w;
        }
        __syncthreads();
#pragma unroll
        for (int kk = 0; kk < 16; ++kk) {
            float4 a0 = *(const float4*)&As[kk][tm * 8];
            float4 a1 = *(const float4*)&As[kk][tm * 8 + 4];
            float4 b0 = *(const float4*)&Bs[kk][tn * 8];
            float4 b1 = *(const float4*)&Bs[kk][tn * 8 + 4];
            float av8[8] = {a0.x, a0.y, a0.z, a0.w, a1.x, a1.y, a1.z, a1.w};
            float bv8[8] = {b0.x, b0.y, b0.z, b0.w, b1.x, b1.y, b1.z, b1.w};
#pragma unroll
            for (int a = 0; a < 8; a++)
#pragma unroll
                for (int b = 0; b < 8; b++) acc[a][b] += av8[a] * bv8[b];
        }
        __syncthreads();
    }
    float bias[8];
#pragma unroll
    for (int b = 0; b < 8; b++) { int g = g0 + tn * 8 + b; bias[b] = bih[g] + bhh[g]; }
#pragma unroll
    for (int a = 0; a < 8; a++) {
        const int t = t0 + tm * 8 + a;
        float* op = zin + (size_t)t * G4 + g0 + tn * 8;
        float4 o0 = {acc[a][0] + bias[0], acc[a][1] + bias[1], acc[a][2] + bias[2], acc[a][3] + bias[3]};
        float4 o1 = {acc[a][4] + bias[4], acc[a][5] + bias[5], acc[a][6] + bias[6], acc[a][7] + bias[7]};
        *(float4*)op = o0; *(float4*)(op + 4) = o1;
    }
}

// ---------------------------------------------------------------------------
// Kernel 2: LSTM recurrence. 64 wgs x 256 threads; wg (d,k) owns hidden units
// [k*16, k*16+16) of direction d.
// Weights: 32 f4 = 128 VGPRs. Loaded with PLAIN vector loads (compiler
// inserts correct waitcnt), then pinned with an opaque identity asm so the
// value becomes a non-rematerializable asm output: the compiler cannot sink
// the loads into the loop (R1 bug), and any spill holds CORRECT data
// (R2-R5 bug was asm loads whose async results got spilled before landing).
// h exchange: write-once 32-bit words, owned sentinel 0xFFFFFFFF. Producer:
// relaxed agent atomic store; consumer polls the data itself with relaxed
// agent 64-bit loads, each half validated independently. Value IS readiness;
// no ordering assumptions.
// ---------------------------------------------------------------------------
__global__ __launch_bounds__(256, 1) void lstm_rec(
    const float* __restrict__ zin_f, const float* __restrict__ zin_b,
    const float* __restrict__ Whh_f, const float* __restrict__ Whh_b,
    unsigned int* __restrict__ hw_f, unsigned int* __restrict__ hw_b)
{
    const int bid = blockIdx.x;
    const int d = bid >> 5;          // 0 fwd, 1 bwd
    const int k = bid & 31;
    const float* zin = d ? zin_b : zin_f;
    const float* Whh = d ? Whh_b : Whh_f;
    unsigned int* hw = d ? hw_b : hw_f;

    const int tid = threadIdx.x;
    const int q = tid >> 6;          // wave = column segment (128 cols)
    const int r = tid & 63;          // gate row within wg
    const int gate = r >> 4, jj = r & 15;
    const int grow = gate * HH + k * 16 + jj;      // global gate row [0,2048)

    const f4* wp = (const f4*)(Whh + (size_t)grow * HH + q * 128);
    f4 w[32];
#pragma unroll
    for (int i = 0; i < 32; ++i) w[i] = wp[i];     // plain loads: correct waitcnt
#pragma unroll
    for (int i = 0; i < 32; ++i)
        asm volatile("" : "+v"(w[i]));             // opaque pin: no remat/sink

    __shared__ float hs[HH];
    __shared__ float zb[256];

    float c = 0.f;
    const int n = k * 16 + tid;      // hidden index (valid for tid<16)
    const int s2 = tid * 2;          // this thread's 2 h-slots

    for (int it = 0; it < TT; ++it) {
        const int t = d ? (TT - 1 - it) : it;

        // zin prefetch (independent of the h chain; issued before the spin)
        float z0 = 0, z1 = 0, z2 = 0, z3 = 0;
        if (tid < 16) {
            const float* zt = zin + (size_t)t * G4 + n;
            z0 = zt[0]; z1 = zt[512]; z2 = zt[1024]; z3 = zt[1536];
        }

        if (it > 0) {
            const int tp = d ? (t + 1) : (t - 1);
            const unsigned long long* hq =
                (const unsigned long long*)(hw + (size_t)tp * HH + s2);
            unsigned long long v;
            do {
                v = __hip_atomic_load(hq, __ATOMIC_RELAXED, __HIP_MEMORY_SCOPE_AGENT);
            } while ((unsigned int)v == SENT || (unsigned int)(v >> 32) == SENT);
            hs[s2]     = __uint_as_float((unsigned int)v);
            hs[s2 + 1] = __uint_as_float((unsigned int)(v >> 32));
        }
        __syncthreads();                                   // B1: hs ready

        float part = 0.f;
        if (it > 0) {
            const f4* hv = ((const f4*)hs) + (q << 5);     // wave-uniform broadcast
#pragma unroll
            for (int i = 0; i < 32; ++i) {
                f4 h4 = hv[i];
                part += w[i].x * h4.x + w[i].y * h4.y + w[i].z * h4.z + w[i].w * h4.w;
            }
        }
        zb[tid] = part;                                    // zb[q*64 + r]
        __syncthreads();                                   // B2: partials ready

        if (tid < 16) {
            float s0 = 0, s1 = 0, sg = 0, s3 = 0;
#pragma unroll
            for (int qq = 0; qq < 4; ++qq) {
                const int b = qq * 64 + tid;
                s0 += zb[b]; s1 += zb[b + 16]; sg += zb[b + 32]; s3 += zb[b + 48];
            }
            const float gi = 1.f / (1.f + expf(-(z0 + s0)));
            const float gf = 1.f / (1.f + expf(-(z1 + s1)));
            const float gg = tanhf(z2 + sg);
            const float go = 1.f / (1.f + expf(-(z3 + s3)));
            c = gf * c + gi * gg;
            const float hval = go * tanhf(c);
            __hip_atomic_store(&hw[(size_t)t * HH + n], __float_as_uint(hval),
                               __ATOMIC_RELAXED, __HIP_MEMORY_SCOPE_AGENT);
        }
        // no third barrier needed: hs(it+1) writes happen after B2(it);
        // zb(it+1) writes happen after B1(it+1), which gate threads reach
        // only after their zb reads.
    }
}

// ---------------------------------------------------------------------------
// Kernel 3: feats[t] = [h_f[t] | h_b[t]] . fc_w[i] + fc_b[i].  One wave per t.
// Plain loads: kernel-boundary coherence (R1-validated).
// ---------------------------------------------------------------------------
__global__ void feats_kernel(const float* __restrict__ h_f, const float* __restrict__ h_b,
                             const float* __restrict__ fc_w, const float* __restrict__ fc_b,
                             float* __restrict__ feats)
{
    const int t = blockIdx.x;
    const int l = threadIdx.x;
    float acc[NC] = {0.f, 0.f, 0.f, 0.f, 0.f};
    for (int m = 0; m < 16; ++m) {
        const int cg = l + m * 64;
        const float hv = (cg < HH) ? h_f[(size_t)t * HH + cg]
                                   : h_b[(size_t)t * HH + cg - HH];
#pragma unroll
        for (int i = 0; i < NC; i++) acc[i] += hv * fc_w[i * (2 * HH) + cg];
    }
#pragma unroll
    for (int i = 0; i < NC; i++) {
#pragma unroll
        for (int off = 32; off; off >>= 1) acc[i] += __shfl_xor(acc[i], off);
    }
    if (l == 0) {
#pragma unroll
        for (int i = 0; i < NC; i++) feats[(size_t)t * NC + i] = acc[i] + fc_b[i];
    }
}

// ---------------------------------------------------------------------------
// Kernel 4: Viterbi forward + backtrack. 1 block, 64 threads.
// ---------------------------------------------------------------------------
__global__ void viterbi_kernel(const float* __restrict__ feats,
                               const float* __restrict__ trans,
                               float* __restrict__ out)
{
    __shared__ float fs[TT * NC];
    __shared__ int par[TT];
    __shared__ float pathv[TT];
    const int tid = threadIdx.x;
    for (int i = tid; i < TT * NC; i += 64) fs[i] = feats[i];
    float tr[25];
#pragma unroll
    for (int i = 0; i < 25; i++) tr[i] = trans[i];
    __syncthreads();

    float layer[NC];
#pragma unroll
    for (int i = 0; i < NC; i++) layer[i] = fs[i] + tr[i * 5 + 3];

    for (int s = 0; s < TT - 1; ++s) {
        const float* ft = &fs[(s + 1) * NC];
        float nl[NC]; int pk = 0;
#pragma unroll
        for (int i = 0; i < NC; i++) {
            float best = tr[i * 5 + 0] + layer[0]; int bj = 0;
#pragma unroll
            for (int jj = 1; jj < NC; jj++) {
                const float v = tr[i * 5 + jj] + layer[jj];
                if (v > best) { best = v; bj = jj; }
            }
            nl[i] = ft[i] + best;
            pk |= bj << (3 * i);
        }
#pragma unroll
        for (int i = 0; i < NC; i++) layer[i] = nl[i];
        if (tid == 0) par[s] = pk;
    }
    float best = layer[0] + tr[20]; int idx0 = 0;
#pragma unroll
    for (int jj = 1; jj < NC; jj++) {
        const float v = layer[jj] + tr[20 + jj];
        if (v > best) { best = v; idx0 = jj; }
    }
    __syncthreads();
    if (tid == 0) {
        pathv[TT - 1] = (float)idx0;
        int idx = idx0;
        for (int s = TT - 2; s >= 0; --s) {
            idx = (par[s] >> (3 * idx)) & 7;
            pathv[s] = (float)idx;
        }
        out[TT] = best;
    }
    __syncthreads();
    for (int i = tid; i < TT; i += 64) out[i] = pathv[i];
}

// ---------------------------------------------------------------------------
extern "C" void kernel_launch(void* const* d_in, const int* in_sizes, int n_in,
                              void* d_out, int out_size, void* d_ws, size_t ws_size,
                              hipStream_t stream) {
    const int*   sent   = (const int*)d_in[0];
    const float* emb    = (const float*)d_in[1];
    const float* Wih_f  = (const float*)d_in[2];
    const float* Whh_f  = (const float*)d_in[3];
    const float* bih_f  = (const float*)d_in[4];
    const float* bhh_f  = (const float*)d_in[5];
    const float* Wih_b  = (const float*)d_in[6];
    const float* Whh_b  = (const float*)d_in[7];
    const float* bih_b  = (const float*)d_in[8];
    const float* bhh_b  = (const float*)d_in[9];
    const float* fc_w   = (const float*)d_in[10];
    const float* fc_b   = (const float*)d_in[11];
    const float* trans  = (const float*)d_in[12];
    float* out = (float*)d_out;

    char* ws = (char*)d_ws;
    float* zin_f = (float*)ws;                                   // 16 MB
    float* zin_b = (float*)(ws + (size_t)16777216);              // 16 MB
    unsigned int* hw_f = (unsigned int*)(ws + (size_t)33554432); // 4 MB
    unsigned int* hw_b = (unsigned int*)(ws + (size_t)37748736); // 4 MB
    float* feats = (float*)(ws + (size_t)41943040);              // 40 KB

    // OWN the sentinel: h buffers = 0xFFFFFFFF (-NaN, impossible h)
    hipMemsetAsync(hw_f, 0xFF, (size_t)8388608, stream);         // covers hw_f + hw_b

    dim3 gg(G4 / 128, TT / 128, 2);
    zin_gemm<<<gg, 256, 0, stream>>>(sent, emb, Wih_f, bih_f, bhh_f,
                                     Wih_b, bih_b, bhh_b, zin_f, zin_b);

    lstm_rec<<<64, 256, 0, stream>>>(zin_f, zin_b, Whh_f, Whh_b, hw_f, hw_b);

    feats_kernel<<<TT, 64, 0, stream>>>((const float*)hw_f, (const float*)hw_b,
                                        fc_w, fc_b, feats);

    viterbi_kernel<<<1, 64, 0, stream>>>(feats, trans, out);
}

// Round 7
// 4769.235 us; speedup vs baseline: 3.1275x; 1.1844x over previous
//
#include <hip/hip_runtime.h>

#define TT 2048
#define WD 768
#define HH 512
#define G4 2048      // 4*H
#define NC 5
#define SENT 0xFFFFFFFFu   // owned sentinel (-NaN); |h|<1 can never produce it.
                           // h buffers memset to 0xFF at every launch.

typedef float f4 __attribute__((ext_vector_type(4)));
typedef unsigned int u4 __attribute__((ext_vector_type(4)));

// ---------------------------------------------------------------------------
// Kernel 1: zin[t][g] = emb[sent[t]] . Wih[g] + bih[g] + bhh[g]   (both dirs)
// ---------------------------------------------------------------------------
__global__ __launch_bounds__(256) void zin_gemm(
    const int* __restrict__ sent, const float* __restrict__ emb,
    const float* __restrict__ Wih_f, const float* __restrict__ bih_f, const float* __restrict__ bhh_f,
    const float* __restrict__ Wih_b, const float* __restrict__ bih_b, const float* __restrict__ bhh_b,
    float* __restrict__ zin_f, float* __restrict__ zin_b)
{
    const int dirn = blockIdx.z;
    const float* Wih = dirn ? Wih_b : Wih_f;
    const float* bih = dirn ? bih_b : bih_f;
    const float* bhh = dirn ? bhh_b : bhh_f;
    float* zin = dirn ? zin_b : zin_f;

    __shared__ float As[16][128];
    __shared__ float Bs[16][128];

    const int tid = threadIdx.x;
    const int t0 = blockIdx.y * 128;
    const int g0 = blockIdx.x * 128;
    const int tm = tid >> 4, tn = tid & 15;

    float acc[8][8];
#pragma unroll
    for (int a = 0; a < 8; a++)
#pragma unroll
        for (int b = 0; b < 8; b++) acc[a][b] = 0.f;

    for (int kt = 0; kt < 48; ++kt) {
        const int k0 = kt * 16;
#pragma unroll
        for (int u = 0; u < 2; ++u) {
            const int s = tid * 2 + u;
            const int m = s >> 2, kq = s & 3;
            const int rowA = sent[t0 + m];
            float4 av = *(const float4*)(emb + (size_t)rowA * WD + k0 + kq * 4);
            As[kq * 4 + 0][m] = av.x; As[kq * 4 + 1][m] = av.y;
            As[kq * 4 + 2][m] = av.z; As[kq * 4 + 3][m] = av.w;
            float4 bv = *(const float4*)(Wih + (size_t)(g0 + m) * WD + k0 + kq * 4);
            Bs[kq * 4 + 0][m] = bv.x; Bs[kq * 4 + 1][m] = bv.y;
            Bs[kq * 4 + 2][m] = bv.z; Bs[kq * 4 + 3][m] = bv.w;
        }
        __syncthreads();
#pragma unroll
        for (int kk = 0; kk < 16; ++kk) {
            float4 a0 = *(const float4*)&As[kk][tm * 8];
            float4 a1 = *(const float4*)&As[kk][tm * 8 + 4];
            float4 b0 = *(const float4*)&Bs[kk][tn * 8];
            float4 b1 = *(const float4*)&Bs[kk][tn * 8 + 4];
            float av8[8] = {a0.x, a0.y, a0.z, a0.w, a1.x, a1.y, a1.z, a1.w};
            float bv8[8] = {b0.x, b0.y, b0.z, b0.w, b1.x, b1.y, b1.z, b1.w};
#pragma unroll
            for (int a = 0; a < 8; a++)
#pragma unroll
                for (int b = 0; b < 8; b++) acc[a][b] += av8[a] * bv8[b];
        }
        __syncthreads();
    }
    float bias[8];
#pragma unroll
    for (int b = 0; b < 8; b++) { int g = g0 + tn * 8 + b; bias[b] = bih[g] + bhh[g]; }
#pragma unroll
    for (int a = 0; a < 8; a++) {
        const int t = t0 + tm * 8 + a;
        float* op = zin + (size_t)t * G4 + g0 + tn * 8;
        float4 o0 = {acc[a][0] + bias[0], acc[a][1] + bias[1], acc[a][2] + bias[2], acc[a][3] + bias[3]};
        float4 o1 = {acc[a][4] + bias[4], acc[a][5] + bias[5], acc[a][6] + bias[6], acc[a][7] + bias[7]};
        *(float4*)op = o0; *(float4*)(op + 4) = o1;
    }
}

// ---------------------------------------------------------------------------
// Kernel 2: LSTM recurrence. 64 wgs x 256 threads; wg (d,k) owns hidden units
// [k*16, k*16+16) of direction d.
// Weights: plain loads (correct waitcnt), pinned into AGPRs ("+a", re-pinned
// per iteration) — gfx950 unified file; dot reads via accvgpr_read, no
// scratch re-fetch (R6: VGPR=80 showed spill-and-reload every step).
// Sync: write-once 32-bit h words, owned sentinel 0xFFFFFFFF. Producer lanes
// store relaxed-agent 4B. ONLY WAVE 0 polls: 64 lanes x 2 device-coherent
// dwordx4 loads (sc0 sc1) = 2 KB, each dword validated independently.
// Waves 1-3 wait at the barrier. Gate phase: 64 lanes of wave0, one
// transcendental each (same formulas/order as R6 -> bit-exact), shfl-combine.
// ---------------------------------------------------------------------------
__global__ __launch_bounds__(256, 1) void lstm_rec(
    const float* __restrict__ zin_f, const float* __restrict__ zin_b,
    const float* __restrict__ Whh_f, const float* __restrict__ Whh_b,
    unsigned int* __restrict__ hw_f, unsigned int* __restrict__ hw_b)
{
    const int bid = blockIdx.x;
    const int d = bid >> 5;          // 0 fwd, 1 bwd
    const int k = bid & 31;
    const float* zin = d ? zin_b : zin_f;
    const float* Whh = d ? Whh_b : Whh_f;
    unsigned int* hw = d ? hw_b : hw_f;

    const int tid = threadIdx.x;
    const int q = tid >> 6;          // wave = column segment (128 cols)
    const int r = tid & 63;          // gate row within wg
    const int gate = r >> 4, jj = r & 15;
    const int grow = gate * HH + k * 16 + jj;      // global gate row [0,2048)

    const f4* wp = (const f4*)(Whh + (size_t)grow * HH + q * 128);
    f4 w[32];
#pragma unroll
    for (int i = 0; i < 32; ++i) w[i] = wp[i];     // plain loads: correct waitcnt
#pragma unroll
    for (int i = 0; i < 32; ++i)
        asm volatile("" : "+a"(w[i]));             // home the values in AGPRs

    __shared__ float hs[HH];
    __shared__ float zb[256];

    float c = 0.f;
    const int l = tid;               // wave0 lane id (used when tid<64)
    const int g = l >> 4, j = l & 15;     // gate / unit for gate phase
    const int n16 = k * 16 + j;           // hidden index for gate phase

    for (int it = 0; it < TT; ++it) {
        const int t = d ? (TT - 1 - it) : it;

        // wave0: zin value for (gate g, unit j) — issued before the poll
        float z = 0.f;
        if (tid < 64) z = zin[(size_t)t * G4 + g * HH + n16];

        if (it > 0 && tid < 64) {
            const int tp = d ? (t + 1) : (t - 1);
            const unsigned int* pa = hw + (size_t)tp * HH + l * 8;
            u4 a0, a1;
            for (;;) {
                asm volatile(
                    "global_load_dwordx4 %0, %2, off sc0 sc1\n\t"
                    "global_load_dwordx4 %1, %2, off offset:16 sc0 sc1\n\t"
                    "s_waitcnt vmcnt(0)"
                    : "=v"(a0), "=v"(a1) : "v"(pa) : "memory");
                if (a0.x != SENT && a0.y != SENT && a0.z != SENT && a0.w != SENT &&
                    a1.x != SENT && a1.y != SENT && a1.z != SENT && a1.w != SENT) break;
            }
            u4* hd = (u4*)(hs + l * 8);
            hd[0] = a0; hd[1] = a1;
        }
        __syncthreads();                                   // B1: hs ready

        // keep weights homed in AGPRs across the loop (re-pin each iter)
#pragma unroll
        for (int i = 0; i < 32; ++i) asm volatile("" : "+a"(w[i]));

        float part = 0.f;
        if (it > 0) {
            const f4* hv = ((const f4*)hs) + (q << 5);     // wave-uniform broadcast
#pragma unroll
            for (int i = 0; i < 32; ++i) {
                f4 h4 = hv[i];
                part += w[i].x * h4.x + w[i].y * h4.y + w[i].z * h4.z + w[i].w * h4.w;
            }
        }
        zb[tid] = part;                                    // zb[q*64 + r]
        __syncthreads();                                   // B2: partials ready

        if (tid < 64) {
            // same summation order as R6 (bit-exact): qq = 0..3
            float s = zb[l] + zb[64 + l] + zb[128 + l] + zb[192 + l];
            const float pre = z + s;
            float act;
            if (g == 2) act = tanhf(pre);                  // g gate
            else        act = 1.f / (1.f + expf(-pre));    // i, f, o gates
            const float gi = __shfl(act, j);
            const float gf = __shfl(act, j + 16);
            const float gg = __shfl(act, j + 32);
            const float go = __shfl(act, j + 48);
            if (l < 16) {
                c = gf * c + gi * gg;
                const float hval = go * tanhf(c);
                __hip_atomic_store(&hw[(size_t)t * HH + k * 16 + l],
                                   __float_as_uint(hval),
                                   __ATOMIC_RELAXED, __HIP_MEMORY_SCOPE_AGENT);
            }
        }
        // 2 barriers suffice: hs(it+1) writes (wave0, after B2(it)) cannot
        // race dot reads of hs(it) (before B2(it)); zb(it+1) writes (after
        // B1(it+1)) cannot race gate-phase zb reads (wave0 reaches B1(it+1)
        // only after finishing them).
    }
}

// ---------------------------------------------------------------------------
// Kernel 3: feats[t] = [h_f[t] | h_b[t]] . fc_w[i] + fc_b[i].  One wave per t.
// ---------------------------------------------------------------------------
__global__ void feats_kernel(const float* __restrict__ h_f, const float* __restrict__ h_b,
                             const float* __restrict__ fc_w, const float* __restrict__ fc_b,
                             float* __restrict__ feats)
{
    const int t = blockIdx.x;
    const int l = threadIdx.x;
    float acc[NC] = {0.f, 0.f, 0.f, 0.f, 0.f};
    for (int m = 0; m < 16; ++m) {
        const int cg = l + m * 64;
        const float hv = (cg < HH) ? h_f[(size_t)t * HH + cg]
                                   : h_b[(size_t)t * HH + cg - HH];
#pragma unroll
        for (int i = 0; i < NC; i++) acc[i] += hv * fc_w[i * (2 * HH) + cg];
    }
#pragma unroll
    for (int i = 0; i < NC; i++) {
#pragma unroll
        for (int off = 32; off; off >>= 1) acc[i] += __shfl_xor(acc[i], off);
    }
    if (l == 0) {
#pragma unroll
        for (int i = 0; i < NC; i++) feats[(size_t)t * NC + i] = acc[i] + fc_b[i];
    }
}

// ---------------------------------------------------------------------------
// Kernel 4: Viterbi forward + backtrack. 1 block, 64 threads.
// ---------------------------------------------------------------------------
__global__ void viterbi_kernel(const float* __restrict__ feats,
                               const float* __restrict__ trans,
                               float* __restrict__ out)
{
    __shared__ float fs[TT * NC];
    __shared__ int par[TT];
    __shared__ float pathv[TT];
    const int tid = threadIdx.x;
    for (int i = tid; i < TT * NC; i += 64) fs[i] = feats[i];
    float tr[25];
#pragma unroll
    for (int i = 0; i < 25; i++) tr[i] = trans[i];
    __syncthreads();

    float layer[NC];
#pragma unroll
    for (int i = 0; i < NC; i++) layer[i] = fs[i] + tr[i * 5 + 3];

    for (int s = 0; s < TT - 1; ++s) {
        const float* ft = &fs[(s + 1) * NC];
        float nl[NC]; int pk = 0;
#pragma unroll
        for (int i = 0; i < NC; i++) {
            float best = tr[i * 5 + 0] + layer[0]; int bj = 0;
#pragma unroll
            for (int jj = 1; jj < NC; jj++) {
                const float v = tr[i * 5 + jj] + layer[jj];
                if (v > best) { best = v; bj = jj; }
            }
            nl[i] = ft[i] + best;
            pk |= bj << (3 * i);
        }
#pragma unroll
        for (int i = 0; i < NC; i++) layer[i] = nl[i];
        if (tid == 0) par[s] = pk;
    }
    float best = layer[0] + tr[20]; int idx0 = 0;
#pragma unroll
    for (int jj = 1; jj < NC; jj++) {
        const float v = layer[jj] + tr[20 + jj];
        if (v > best) { best = v; idx0 = jj; }
    }
    __syncthreads();
    if (tid == 0) {
        pathv[TT - 1] = (float)idx0;
        int idx = idx0;
        for (int s = TT - 2; s >= 0; --s) {
            idx = (par[s] >> (3 * idx)) & 7;
            pathv[s] = (float)idx;
        }
        out[TT] = best;
    }
    __syncthreads();
    for (int i = tid; i < TT; i += 64) out[i] = pathv[i];
}

// ---------------------------------------------------------------------------
extern "C" void kernel_launch(void* const* d_in, const int* in_sizes, int n_in,
                              void* d_out, int out_size, void* d_ws, size_t ws_size,
                              hipStream_t stream) {
    const int*   sent   = (const int*)d_in[0];
    const float* emb    = (const float*)d_in[1];
    const float* Wih_f  = (const float*)d_in[2];
    const float* Whh_f  = (const float*)d_in[3];
    const float* bih_f  = (const float*)d_in[4];
    const float* bhh_f  = (const float*)d_in[5];
    const float* Wih_b  = (const float*)d_in[6];
    const float* Whh_b  = (const float*)d_in[7];
    const float* bih_b  = (const float*)d_in[8];
    const float* bhh_b  = (const float*)d_in[9];
    const float* fc_w   = (const float*)d_in[10];
    const float* fc_b   = (const float*)d_in[11];
    const float* trans  = (const float*)d_in[12];
    float* out = (float*)d_out;

    char* ws = (char*)d_ws;
    float* zin_f = (float*)ws;                                   // 16 MB
    float* zin_b = (float*)(ws + (size_t)16777216);              // 16 MB
    unsigned int* hw_f = (unsigned int*)(ws + (size_t)33554432); // 4 MB
    unsigned int* hw_b = (unsigned int*)(ws + (size_t)37748736); // 4 MB
    float* feats = (float*)(ws + (size_t)41943040);              // 40 KB

    // OWN the sentinel: h buffers = 0xFFFFFFFF (-NaN, impossible h)
    hipMemsetAsync(hw_f, 0xFF, (size_t)8388608, stream);         // covers hw_f + hw_b

    dim3 gg(G4 / 128, TT / 128, 2);
    zin_gemm<<<gg, 256, 0, stream>>>(sent, emb, Wih_f, bih_f, bhh_f,
                                     Wih_b, bih_b, bhh_b, zin_f, zin_b);

    lstm_rec<<<64, 256, 0, stream>>>(zin_f, zin_b, Whh_f, Whh_b, hw_f, hw_b);

    feats_kernel<<<TT, 64, 0, stream>>>((const float*)hw_f, (const float*)hw_b,
                                        fc_w, fc_b, feats);

    viterbi_kernel<<<1, 64, 0, stream>>>(feats, trans, out);
}